// Round 4
// baseline (39.177 us; speedup 1.0000x reference)
//
#include <hip/hip_runtime.h>

#define B 32
#define S 512
#define D 384
#define T 3072
#define FPB 64             // frames per gather block
#define D4 (D/4)           // 96 float4 per frame
#define NT 256
#define BPR (T/FPB)        // 48 blocks per batch row
#define NBLK (BPR*B)       // 1536 gather blocks
#define NXCD 8

typedef float f32x4 __attribute__((ext_vector_type(4)));

// d_out offsets (floats), concatenated in reference return order
#define OFF_OUT  0
#define OFF_DUR  (B*T*D)
#define OFF_MLEN (OFF_DUR + B*S)
#define OFF_MASK (OFF_MLEN + B)

// ws layout: idx[B*T] ints, then mlen[B] ints

// ---- Phase 1: durations, cumsum, and scatter of searchsorted-inverse ----
// idx[b,t] = s for t in [cum[s-1], cum[s]) ; frames >= mel_len are don't-care
// (gather guards with t < mlen and never reads their idx).
__global__ __launch_bounds__(512) void durations_kernel(
    const float* __restrict__ logd, const int* __restrict__ max_len_p,
    float* __restrict__ out, int* __restrict__ idx_ws, int* __restrict__ mlen_ws)
{
    const int b = blockIdx.x;
    const int s = threadIdx.x;

    float ld = logd[b * S + s];
    float dr = fmaxf(rintf(expf(ld) - 1.0f), 0.0f);  // rintf = half-even, matches jnp.round
    int d = (int)dr;
    out[OFF_DUR + b * S + s] = dr;

    // inclusive scan across 512 threads
    const int lane = s & 63;
    const int wave = s >> 6;
    int v = d;
    #pragma unroll
    for (int off = 1; off < 64; off <<= 1) {
        int u = __shfl_up(v, off, 64);
        if (lane >= off) v += u;
    }
    __shared__ int wsum[8];
    if (lane == 63) wsum[wave] = v;
    __syncthreads();
    if (s == 0) {
        int acc = 0;
        #pragma unroll
        for (int w = 0; w < 8; ++w) { int t = wsum[w]; wsum[w] = acc; acc += t; }
    }
    __syncthreads();
    const int inc = v + wsum[wave];       // inclusive cumsum through s
    const int start = inc - d;            // exclusive prefix
    const int end = min(inc, T);
    for (int t = start; t < end; ++t) idx_ws[b * T + t] = s;

    if (s == S - 1) {
        int ml = min(inc, max_len_p[0]);
        mlen_ws[b] = ml;
        out[OFF_MLEN + b] = (float)ml;
    }
}

// ---- Phase 2: pure gather-copy (no search, no scan) ----
__global__ __launch_bounds__(NT) void gather_kernel(
    const float* __restrict__ x, const int* __restrict__ idx_ws,
    const int* __restrict__ mlen_ws, float* __restrict__ outp)
{
    __shared__ int sidx[FPB];
    __shared__ int mlen_sh;

    // chunked XCD swizzle: 1536 blocks -> 8 chunks of 192 (= 4 full rows per
    // XCD; 4 x-rows = 3.2 MB fits the 4 MiB per-XCD L2)
    const int lin = blockIdx.x;
    const int swz = (lin & (NXCD - 1)) * (NBLK / NXCD) + (lin >> 3);
    const int b   = swz / BPR;
    const int t0  = (swz % BPR) * FPB;
    const int tid = threadIdx.x;

    if (tid == 0) mlen_sh = mlen_ws[b];
    if (tid < FPB) sidx[tid] = idx_ws[b * T + t0 + tid];
    __syncthreads();
    const int mlen = mlen_sh;

    if (tid < FPB) {
        const int t = t0 + tid;
        __builtin_nontemporal_store((t < mlen) ? 0.0f : 1.0f,
                                    &outp[OFF_MASK + (size_t)b * T + t]);
    }

    const f32x4* x4 = (const f32x4*)(x + (size_t)b * S * D);
    f32x4* o4 = (f32x4*)(outp + OFF_OUT + (size_t)b * T * D + (size_t)t0 * D);

    #pragma unroll
    for (int i = 0; i < (FPB * D4) / NT; ++i) {   // 24 iterations
        int w = tid + i * NT;
        int f = w / D4;
        int e = w - f * D4;
        int t = t0 + f;
        f32x4 val = (f32x4)(0.f);
        if (t < mlen) val = x4[(size_t)sidx[f] * D4 + e];
        __builtin_nontemporal_store(val, &o4[(size_t)f * D4 + e]);
    }
}

extern "C" void kernel_launch(void* const* d_in, const int* in_sizes, int n_in,
                              void* d_out, int out_size, void* d_ws, size_t ws_size,
                              hipStream_t stream) {
    const float* x      = (const float*)d_in[0];
    const float* logd   = (const float*)d_in[1];
    const int*   maxlen = (const int*)d_in[2];
    float* out = (float*)d_out;

    int* idx_ws  = (int*)d_ws;
    int* mlen_ws = idx_ws + B * T;

    durations_kernel<<<B, 512, 0, stream>>>(logd, maxlen, out, idx_ws, mlen_ws);
    gather_kernel<<<NBLK, NT, 0, stream>>>(x, idx_ws, mlen_ws, out);
}

// Round 5
// 33.634 us; speedup vs baseline: 1.1648x; 1.1648x over previous
//
#include <hip/hip_runtime.h>

#define B 32
#define S 512
#define D 384
#define T 3072
#define FPB 64             // frames per gather block
#define D4 (D/4)           // 96 float4 per frame
#define NT 256

typedef float f32x4 __attribute__((ext_vector_type(4)));

// d_out offsets (floats), concatenated in reference return order
#define OFF_OUT  0
#define OFF_DUR  (B*T*D)
#define OFF_MLEN (OFF_DUR + B*S)
#define OFF_MASK (OFF_MLEN + B)

// ws layout: idx[B*T] ints, then mlen[B] ints

// ---- Phase 1: durations, cumsum, scatter the searchsorted-inverse ----
// idx[b,t] = s for t in [cum[s-1], cum[s]) (disjoint ranges; dur==0 phonemes
// write nothing, matching searchsorted side='right'). Frames >= mel_len are
// never read by the gather (guarded by t < mlen), so their idx is don't-care.
__global__ __launch_bounds__(512) void durations_kernel(
    const float* __restrict__ logd, const int* __restrict__ max_len_p,
    float* __restrict__ out, int* __restrict__ idx_ws, int* __restrict__ mlen_ws)
{
    const int b = blockIdx.x;
    const int s = threadIdx.x;

    float ld = logd[b * S + s];
    float dr = fmaxf(rintf(expf(ld) - 1.0f), 0.0f);  // rintf = half-even, matches jnp.round
    int d = (int)dr;
    out[OFF_DUR + b * S + s] = dr;

    // inclusive scan across 512 threads
    const int lane = s & 63;
    const int wave = s >> 6;
    int v = d;
    #pragma unroll
    for (int off = 1; off < 64; off <<= 1) {
        int u = __shfl_up(v, off, 64);
        if (lane >= off) v += u;
    }
    __shared__ int wsum[8];
    if (lane == 63) wsum[wave] = v;
    __syncthreads();
    if (s == 0) {
        int acc = 0;
        #pragma unroll
        for (int w = 0; w < 8; ++w) { int t = wsum[w]; wsum[w] = acc; acc += t; }
    }
    __syncthreads();
    const int inc = v + wsum[wave];       // inclusive cumsum through s
    const int start = inc - d;            // exclusive prefix
    const int end = min(inc, T);
    for (int t = start; t < end; ++t) idx_ws[b * T + t] = s;

    if (s == S - 1) {
        int ml = min(inc, max_len_p[0]);
        mlen_ws[b] = ml;
        out[OFF_MLEN + b] = (float)ml;
    }
}

// ---- Phase 2: pure gather-copy (no search, no scan, plain stores) ----
__global__ __launch_bounds__(NT) void gather_kernel(
    const float* __restrict__ x, const int* __restrict__ idx_ws,
    const int* __restrict__ mlen_ws, float* __restrict__ outp)
{
    __shared__ int sidx[FPB];
    __shared__ int mlen_sh;

    const int b   = blockIdx.y;
    const int t0  = blockIdx.x * FPB;
    const int tid = threadIdx.x;

    if (tid < FPB) sidx[tid] = idx_ws[b * T + t0 + tid];
    if (tid == NT - 1) mlen_sh = mlen_ws[b];
    __syncthreads();
    const int mlen = mlen_sh;

    if (tid < FPB) {
        const int t = t0 + tid;
        outp[OFF_MASK + (size_t)b * T + t] = (t < mlen) ? 0.0f : 1.0f;
    }

    const f32x4* x4 = (const f32x4*)(x + (size_t)b * S * D);
    f32x4* o4 = (f32x4*)(outp + OFF_OUT + (size_t)b * T * D + (size_t)t0 * D);

    #pragma unroll
    for (int i = 0; i < (FPB * D4) / NT; ++i) {   // 24 iterations, 4 KB/wave-instr
        int w = tid + i * NT;
        int f = w / D4;
        int e = w - f * D4;
        int t = t0 + f;
        f32x4 val = (f32x4)(0.f);
        if (t < mlen) val = x4[(size_t)sidx[f] * D4 + e];
        o4[(size_t)f * D4 + e] = val;
    }
}

extern "C" void kernel_launch(void* const* d_in, const int* in_sizes, int n_in,
                              void* d_out, int out_size, void* d_ws, size_t ws_size,
                              hipStream_t stream) {
    const float* x      = (const float*)d_in[0];
    const float* logd   = (const float*)d_in[1];
    const int*   maxlen = (const int*)d_in[2];
    float* out = (float*)d_out;

    int* idx_ws  = (int*)d_ws;
    int* mlen_ws = idx_ws + B * T;

    durations_kernel<<<B, 512, 0, stream>>>(logd, maxlen, out, idx_ws, mlen_ws);
    gather_kernel<<<dim3(T / FPB, B), NT, 0, stream>>>(x, idx_ws, mlen_ws, out);
}